// Round 1
// baseline (546.516 us; speedup 1.0000x reference)
//
#include <hip/hip_runtime.h>

#define TILE  4096
#define BLK   256
#define NBUCK 64

__device__ __forceinline__ int compute_bid(float px, float py, float pz,
                                           float a0x, float a0y, float a0z,
                                           float vx, float vy, float vz) {
    // idx = floor((p - aabb0) / voxel), clamp to [0,3]; bid = ix*16 + iy*4 + iz
    int ix = (int)floorf((px - a0x) / vx);
    int iy = (int)floorf((py - a0y) / vy);
    int iz = (int)floorf((pz - a0z) / vz);
    ix = min(max(ix, 0), 3);
    iy = min(max(iy, 0), 3);
    iz = min(max(iz, 0), 3);
    return ix * 16 + iy * 4 + iz;
}

// Pass 1: per-tile 64-bin histograms, stored bucket-major hist[b*G + g]
__global__ void hist_kernel(const float* __restrict__ xyz,
                            const float* __restrict__ aabb,
                            int* __restrict__ hist, int N, int G) {
    __shared__ int s_h[NBUCK];
    const int tid = threadIdx.x, g = blockIdx.x;
    if (tid < NBUCK) s_h[tid] = 0;
    __syncthreads();
    const float a0x = aabb[0], a0y = aabb[1], a0z = aabb[2];
    const float vx = (aabb[3] - a0x) * 0.25f;   // /4.0f exact (pow2)
    const float vy = (aabb[4] - a0y) * 0.25f;
    const float vz = (aabb[5] - a0z) * 0.25f;
    for (int c = 0; c < TILE / BLK; ++c) {
        int i = g * TILE + c * BLK + tid;
        if (i < N) {
            float px = xyz[3 * i], py = xyz[3 * i + 1], pz = xyz[3 * i + 2];
            int b = compute_bid(px, py, pz, a0x, a0y, a0z, vx, vy, vz);
            atomicAdd(&s_h[b], 1);
        }
    }
    __syncthreads();
    if (tid < NBUCK) hist[tid * G + g] = s_h[tid];
}

// Pass 2: single-block exclusive scan over 64*G ints (bucket-major flat order)
__global__ void scan_kernel(int* __restrict__ hist, int total) {
    __shared__ int s[BLK];
    const int tid = threadIdx.x;
    const int per = (total + BLK - 1) / BLK;
    const int lo = tid * per;
    const int hi = min(lo + per, total);
    int sum = 0;
    for (int k = lo; k < hi; ++k) sum += hist[k];
    s[tid] = sum;
    __syncthreads();
    for (int off = 1; off < BLK; off <<= 1) {
        int v = (tid >= off) ? s[tid - off] : 0;
        __syncthreads();
        s[tid] += v;
        __syncthreads();
    }
    int run = (tid == 0) ? 0 : s[tid - 1];
    for (int k = lo; k < hi; ++k) {
        int v = hist[k];
        hist[k] = run;
        run += v;
    }
}

// Pass 3: stable in-tile scatter + trilinear alpha compute, out[pos] = alpha
__global__ void scatter_kernel(const float* __restrict__ xyz,
                               const float* __restrict__ aabb,
                               const float* __restrict__ vol,
                               const float* __restrict__ dmin,
                               const float* __restrict__ dmax,
                               const int* __restrict__ hist,
                               float* __restrict__ out, int N, int G) {
    __shared__ int   s_cnt[NBUCK];      // running output offset per bucket
    __shared__ int   s_whist[4][NBUCK]; // per-wave per-bucket chunk counts
    __shared__ float s_dmin[192], s_dmax[192];
    const int tid = threadIdx.x, g = blockIdx.x;
    if (tid < NBUCK) s_cnt[tid] = hist[tid * G + g];
    for (int i = tid; i < 192; i += BLK) {
        s_dmin[i] = dmin[i];
        s_dmax[i] = dmax[i];
    }
    const float a0x = aabb[0], a0y = aabb[1], a0z = aabb[2];
    const float vx = (aabb[3] - a0x) * 0.25f;
    const float vy = (aabb[4] - a0y) * 0.25f;
    const float vz = (aabb[5] - a0z) * 0.25f;
    __syncthreads();

    const int lane = tid & 63;
    const int wv = tid >> 6;
    const unsigned long long lt = (1ull << lane) - 1ull;

    for (int c = 0; c < TILE / BLK; ++c) {
        int i = g * TILE + c * BLK + tid;
        bool valid = (i < N);
        int b = 0;
        float alpha = 0.0f;
        if (valid) {
            float px = xyz[3 * i], py = xyz[3 * i + 1], pz = xyz[3 * i + 2];
            b = compute_bid(px, py, pz, a0x, a0y, a0z, vx, vy, vz);
            // local coords in [-1,1]^3 (kilonerf global_to_local)
            float dn0 = s_dmin[3 * b], dn1 = s_dmin[3 * b + 1], dn2 = s_dmin[3 * b + 2];
            float dM0 = s_dmax[3 * b], dM1 = s_dmax[3 * b + 1], dM2 = s_dmax[3 * b + 2];
            float lx = 2.0f * (px - dn0) / (dM0 - dn0) - 1.0f;
            float ly = 2.0f * (py - dn1) / (dM1 - dn1) - 1.0f;
            float lz = 2.0f * (pz - dn2) / (dM2 - dn2) - 1.0f;
            // grid_sample, align_corners=True, W=H=D=64
            float fx = (lx + 1.0f) * 0.5f * 63.0f;
            float fy = (ly + 1.0f) * 0.5f * 63.0f;
            float fz = (lz + 1.0f) * 0.5f * 63.0f;
            float x0f = floorf(fx), y0f = floorf(fy), z0f = floorf(fz);
            float wx = fx - x0f, wy = fy - y0f, wz = fz - z0f;
            int x0 = (int)x0f, y0 = (int)y0f, z0 = (int)z0f;
            const float* vb = vol + ((size_t)b << 18);  // bid * 64^3
            auto F = [&](int zi, int yi, int xi) -> float {
                if ((unsigned)zi >= 64u || (unsigned)yi >= 64u || (unsigned)xi >= 64u)
                    return 0.0f;
                return vb[(zi << 12) + (yi << 6) + xi];
            };
            float s = 0.0f;
            s += (1.0f - wz) * (1.0f - wy) * (1.0f - wx) * F(z0,     y0,     x0);
            s += (1.0f - wz) * (1.0f - wy) * wx          * F(z0,     y0,     x0 + 1);
            s += (1.0f - wz) * wy          * (1.0f - wx) * F(z0,     y0 + 1, x0);
            s += (1.0f - wz) * wy          * wx          * F(z0,     y0 + 1, x0 + 1);
            s += wz          * (1.0f - wy) * (1.0f - wx) * F(z0 + 1, y0,     x0);
            s += wz          * (1.0f - wy) * wx          * F(z0 + 1, y0,     x0 + 1);
            s += wz          * wy          * (1.0f - wx) * F(z0 + 1, y0 + 1, x0);
            s += wz          * wy          * wx          * F(z0 + 1, y0 + 1, x0 + 1);
            alpha = s;
        }
        // zero the 4x64 per-wave histogram (exactly 256 ints, one per thread)
        ((int*)s_whist)[tid] = 0;
        __syncthreads();
        // match-any over 6-bit bucket id within the wave (invalid lanes excluded)
        unsigned long long m = __ballot(valid);
        #pragma unroll
        for (int k = 0; k < 6; ++k) {
            unsigned long long bal = __ballot((b >> k) & 1);
            m &= ((b >> k) & 1) ? bal : ~bal;
        }
        int rank = __popcll(m & lt);
        if (valid && rank == 0) s_whist[wv][b] = __popcll(m);  // group leader
        __syncthreads();
        if (valid) {
            int pos = s_cnt[b] + rank;
            for (int w2 = 0; w2 < wv; ++w2) pos += s_whist[w2][b];
            out[pos] = alpha;
        }
        __syncthreads();
        if (tid < NBUCK)
            s_cnt[tid] += s_whist[0][tid] + s_whist[1][tid] +
                          s_whist[2][tid] + s_whist[3][tid];
        __syncthreads();
    }
}

extern "C" void kernel_launch(void* const* d_in, const int* in_sizes, int n_in,
                              void* d_out, int out_size, void* d_ws, size_t ws_size,
                              hipStream_t stream) {
    const float* xyz  = (const float*)d_in[0];
    const float* aabb = (const float*)d_in[1];
    const float* vol  = (const float*)d_in[2];
    const float* dmin = (const float*)d_in[3];
    const float* dmax = (const float*)d_in[4];
    float* out = (float*)d_out;
    const int N = in_sizes[0] / 3;
    const int G = (N + TILE - 1) / TILE;
    int* hist = (int*)d_ws;  // 64*G ints = 256 KB at N=4.19M

    hist_kernel<<<G, BLK, 0, stream>>>(xyz, aabb, hist, N, G);
    scan_kernel<<<1, BLK, 0, stream>>>(hist, NBUCK * G);
    scatter_kernel<<<G, BLK, 0, stream>>>(xyz, aabb, vol, dmin, dmax, hist, out, N, G);
}

// Round 2
// 308.460 us; speedup vs baseline: 1.7718x; 1.7718x over previous
//
#include <hip/hip_runtime.h>

#define TILE  4096
#define BLK   256
#define NBUCK 64

__device__ __forceinline__ int compute_bid(float px, float py, float pz,
                                           float a0x, float a0y, float a0z,
                                           float vx, float vy, float vz) {
    // idx = floor((p - aabb0) / voxel), clamp to [0,3]; bid = ix*16 + iy*4 + iz
    int ix = (int)floorf((px - a0x) / vx);
    int iy = (int)floorf((py - a0y) / vy);
    int iz = (int)floorf((pz - a0z) / vz);
    ix = min(max(ix, 0), 3);
    iy = min(max(iy, 0), 3);
    iz = min(max(iz, 0), 3);
    return ix * 16 + iy * 4 + iz;
}

// Pass 1: per-tile 64-bin histograms, stored bucket-major hist[b*G + g]
__global__ void hist_kernel(const float* __restrict__ xyz,
                            const float* __restrict__ aabb,
                            int* __restrict__ hist, int N, int G) {
    __shared__ int s_h[NBUCK];
    const int tid = threadIdx.x, g = blockIdx.x;
    if (tid < NBUCK) s_h[tid] = 0;
    __syncthreads();
    const float a0x = aabb[0], a0y = aabb[1], a0z = aabb[2];
    const float vx = (aabb[3] - a0x) * 0.25f;
    const float vy = (aabb[4] - a0y) * 0.25f;
    const float vz = (aabb[5] - a0z) * 0.25f;
    for (int c = 0; c < TILE / BLK; ++c) {
        int i = g * TILE + c * BLK + tid;
        if (i < N) {
            float px = xyz[3 * i], py = xyz[3 * i + 1], pz = xyz[3 * i + 2];
            int b = compute_bid(px, py, pz, a0x, a0y, a0z, vx, vy, vz);
            atomicAdd(&s_h[b], 1);
        }
    }
    __syncthreads();
    if (tid < NBUCK) hist[tid * G + g] = s_h[tid];
}

// Pass 2a: per-bucket row scan. Block b exclusive-scans hist[b*G .. b*G+G),
// in place, and writes the row total to tot[b].
__global__ void scan_rows_kernel(int* __restrict__ hist, int* __restrict__ tot, int G) {
    __shared__ int sh[BLK];
    const int b = blockIdx.x, t = threadIdx.x;
    const int L = (G + BLK - 1) / BLK;
    const int lo = t * L;
    const int n = min(L, max(0, G - lo));
    const int base = b * G + lo;
    int s = 0;
    for (int k = 0; k < n; ++k) s += hist[base + k];
    sh[t] = s;
    __syncthreads();
    for (int off = 1; off < BLK; off <<= 1) {
        int v = (t >= off) ? sh[t - off] : 0;
        __syncthreads();
        sh[t] += v;
        __syncthreads();
    }
    int excl = (t == 0) ? 0 : sh[t - 1];
    for (int k = 0; k < n; ++k) {
        int v = hist[base + k];
        hist[base + k] = excl;
        excl += v;
    }
    if (t == BLK - 1) tot[b] = sh[BLK - 1];
}

// Pass 2b: exclusive scan of the 64 bucket totals -> global bucket offsets.
__global__ void scan_buckets_kernel(const int* __restrict__ tot, int* __restrict__ off) {
    __shared__ int sh[NBUCK];
    const int t = threadIdx.x;
    sh[t] = tot[t];
    __syncthreads();
    for (int o = 1; o < NBUCK; o <<= 1) {
        int v = (t >= o) ? sh[t - o] : 0;
        __syncthreads();
        sh[t] += v;
        __syncthreads();
    }
    off[t] = (t == 0) ? 0 : sh[t - 1];
}

// Pass 3: stable in-tile scatter of the PERMUTATION: perm[pos] = i.
__global__ void scatter_perm_kernel(const float* __restrict__ xyz,
                                    const float* __restrict__ aabb,
                                    const int* __restrict__ hist,
                                    const int* __restrict__ off,
                                    int* __restrict__ perm, int N, int G) {
    __shared__ int s_cnt[NBUCK];        // running output offset per bucket
    __shared__ int s_whist[4][NBUCK];   // per-wave per-bucket chunk counts
    const int tid = threadIdx.x, g = blockIdx.x;
    if (tid < NBUCK) s_cnt[tid] = hist[tid * G + g] + off[tid];
    const float a0x = aabb[0], a0y = aabb[1], a0z = aabb[2];
    const float vx = (aabb[3] - a0x) * 0.25f;
    const float vy = (aabb[4] - a0y) * 0.25f;
    const float vz = (aabb[5] - a0z) * 0.25f;
    __syncthreads();

    const int lane = tid & 63;
    const int wv = tid >> 6;
    const unsigned long long lt = (1ull << lane) - 1ull;

    for (int c = 0; c < TILE / BLK; ++c) {
        int i = g * TILE + c * BLK + tid;
        bool valid = (i < N);
        int b = 0;
        if (valid) {
            float px = xyz[3 * i], py = xyz[3 * i + 1], pz = xyz[3 * i + 2];
            b = compute_bid(px, py, pz, a0x, a0y, a0z, vx, vy, vz);
        }
        ((int*)s_whist)[tid] = 0;
        __syncthreads();
        // match-any over the 6-bit bucket id within the wave
        unsigned long long m = __ballot(valid);
        #pragma unroll
        for (int k = 0; k < 6; ++k) {
            unsigned long long bal = __ballot((b >> k) & 1);
            m &= ((b >> k) & 1) ? bal : ~bal;
        }
        int rank = __popcll(m & lt);
        if (valid && rank == 0) s_whist[wv][b] = __popcll(m);
        __syncthreads();
        if (valid) {
            int pos = s_cnt[b] + rank;
            for (int w2 = 0; w2 < wv; ++w2) pos += s_whist[w2][b];
            perm[pos] = i;
        }
        __syncthreads();
        if (tid < NBUCK)
            s_cnt[tid] += s_whist[0][tid] + s_whist[1][tid] +
                          s_whist[2][tid] + s_whist[3][tid];
        __syncthreads();
    }
}

// Pass 4: walk output in sorted order -> bucket-local volume gathers.
__global__ void gather_out_kernel(const float* __restrict__ xyz,
                                  const float* __restrict__ aabb,
                                  const float* __restrict__ vol,
                                  const float* __restrict__ dmin,
                                  const float* __restrict__ dmax,
                                  const int* __restrict__ perm,
                                  float* __restrict__ out, int N) {
    __shared__ float s_dmin[192], s_dmax[192];
    const int tid = threadIdx.x;
    for (int i = tid; i < 192; i += BLK) {
        s_dmin[i] = dmin[i];
        s_dmax[i] = dmax[i];
    }
    // XCD swizzle: dispatch d -> logical block so each XCD gets a contiguous
    // range of sorted output (volume gathers stay in that XCD's L2).
    int nb = gridDim.x;
    int d = blockIdx.x;
    int lb = (nb % 8 == 0) ? (d % 8) * (nb / 8) + (d / 8) : d;
    const float a0x = aabb[0], a0y = aabb[1], a0z = aabb[2];
    const float vx = (aabb[3] - a0x) * 0.25f;
    const float vy = (aabb[4] - a0y) * 0.25f;
    const float vz = (aabb[5] - a0z) * 0.25f;
    __syncthreads();

    int j = lb * BLK + tid;
    if (j >= N) return;
    int i = perm[j];
    float px = xyz[3 * i], py = xyz[3 * i + 1], pz = xyz[3 * i + 2];
    int b = compute_bid(px, py, pz, a0x, a0y, a0z, vx, vy, vz);
    float dn0 = s_dmin[3 * b], dn1 = s_dmin[3 * b + 1], dn2 = s_dmin[3 * b + 2];
    float dM0 = s_dmax[3 * b], dM1 = s_dmax[3 * b + 1], dM2 = s_dmax[3 * b + 2];
    float lx = 2.0f * (px - dn0) / (dM0 - dn0) - 1.0f;
    float ly = 2.0f * (py - dn1) / (dM1 - dn1) - 1.0f;
    float lz = 2.0f * (pz - dn2) / (dM2 - dn2) - 1.0f;
    float fx = (lx + 1.0f) * 0.5f * 63.0f;
    float fy = (ly + 1.0f) * 0.5f * 63.0f;
    float fz = (lz + 1.0f) * 0.5f * 63.0f;
    float x0f = floorf(fx), y0f = floorf(fy), z0f = floorf(fz);
    float wx = fx - x0f, wy = fy - y0f, wz = fz - z0f;
    int x0 = (int)x0f, y0 = (int)y0f, z0 = (int)z0f;
    const float* vb = vol + ((size_t)b << 18);
    auto F = [&](int zi, int yi, int xi) -> float {
        if ((unsigned)zi >= 64u || (unsigned)yi >= 64u || (unsigned)xi >= 64u)
            return 0.0f;
        return vb[(zi << 12) + (yi << 6) + xi];
    };
    float s = 0.0f;
    s += (1.0f - wz) * (1.0f - wy) * (1.0f - wx) * F(z0,     y0,     x0);
    s += (1.0f - wz) * (1.0f - wy) * wx          * F(z0,     y0,     x0 + 1);
    s += (1.0f - wz) * wy          * (1.0f - wx) * F(z0,     y0 + 1, x0);
    s += (1.0f - wz) * wy          * wx          * F(z0,     y0 + 1, x0 + 1);
    s += wz          * (1.0f - wy) * (1.0f - wx) * F(z0 + 1, y0,     x0);
    s += wz          * (1.0f - wy) * wx          * F(z0 + 1, y0,     x0 + 1);
    s += wz          * wy          * (1.0f - wx) * F(z0 + 1, y0 + 1, x0);
    s += wz          * wy          * wx          * F(z0 + 1, y0 + 1, x0 + 1);
    out[j] = s;
}

extern "C" void kernel_launch(void* const* d_in, const int* in_sizes, int n_in,
                              void* d_out, int out_size, void* d_ws, size_t ws_size,
                              hipStream_t stream) {
    const float* xyz  = (const float*)d_in[0];
    const float* aabb = (const float*)d_in[1];
    const float* vol  = (const float*)d_in[2];
    const float* dmin = (const float*)d_in[3];
    const float* dmax = (const float*)d_in[4];
    float* out = (float*)d_out;
    const int N = in_sizes[0] / 3;
    const int G = (N + TILE - 1) / TILE;

    // ws layout: hist[64*G] | tot[64] | off[64] | perm[N]
    char* ws = (char*)d_ws;
    int* hist = (int*)ws;
    int* tot  = (int*)(ws + (size_t)NBUCK * G * 4);
    int* off  = (int*)(ws + (size_t)NBUCK * G * 4 + 256);
    int* perm = (int*)(ws + (size_t)NBUCK * G * 4 + 512);

    hist_kernel<<<G, BLK, 0, stream>>>(xyz, aabb, hist, N, G);
    scan_rows_kernel<<<NBUCK, BLK, 0, stream>>>(hist, tot, G);
    scan_buckets_kernel<<<1, NBUCK, 0, stream>>>(tot, off);
    scatter_perm_kernel<<<G, BLK, 0, stream>>>(xyz, aabb, hist, off, perm, N, G);
    gather_out_kernel<<<(N + BLK - 1) / BLK, BLK, 0, stream>>>(
        xyz, aabb, vol, dmin, dmax, perm, out, N);
}

// Round 3
// 291.968 us; speedup vs baseline: 1.8718x; 1.0565x over previous
//
#include <hip/hip_runtime.h>

#define TILE  4096
#define BLK   256
#define NBUCK 64

__device__ __forceinline__ int compute_bid(float px, float py, float pz,
                                           float a0x, float a0y, float a0z,
                                           float vx, float vy, float vz) {
    // idx = floor((p - aabb0) / voxel), clamp to [0,3]; bid = ix*16 + iy*4 + iz
    int ix = (int)floorf((px - a0x) / vx);
    int iy = (int)floorf((py - a0y) / vy);
    int iz = (int)floorf((pz - a0z) / vz);
    ix = min(max(ix, 0), 3);
    iy = min(max(iy, 0), 3);
    iz = min(max(iz, 0), 3);
    return ix * 16 + iy * 4 + iz;
}

// Pass 1: per-tile 64-bin histograms, stored bucket-major hist[b*G + g].
// xyz read vectorized: 3x float4 = 4 points per thread per iteration.
__global__ void hist_kernel(const float* __restrict__ xyz,
                            const float* __restrict__ aabb,
                            int* __restrict__ hist, int N, int G) {
    __shared__ int s_h[NBUCK];
    const int tid = threadIdx.x, g = blockIdx.x;
    if (tid < NBUCK) s_h[tid] = 0;
    __syncthreads();
    const float a0x = aabb[0], a0y = aabb[1], a0z = aabb[2];
    const float vx = (aabb[3] - a0x) * 0.25f;
    const float vy = (aabb[4] - a0y) * 0.25f;
    const float vz = (aabb[5] - a0z) * 0.25f;
    for (int c = 0; c < TILE / (BLK * 4); ++c) {
        int p0 = g * TILE + c * (BLK * 4) + tid * 4;
        if (p0 + 3 < N) {
            const float4* v4 = (const float4*)(xyz + (size_t)p0 * 3);
            float4 f0 = v4[0], f1 = v4[1], f2 = v4[2];
            int b0 = compute_bid(f0.x, f0.y, f0.z, a0x, a0y, a0z, vx, vy, vz);
            int b1 = compute_bid(f0.w, f1.x, f1.y, a0x, a0y, a0z, vx, vy, vz);
            int b2 = compute_bid(f1.z, f1.w, f2.x, a0x, a0y, a0z, vx, vy, vz);
            int b3 = compute_bid(f2.y, f2.z, f2.w, a0x, a0y, a0z, vx, vy, vz);
            atomicAdd(&s_h[b0], 1);
            atomicAdd(&s_h[b1], 1);
            atomicAdd(&s_h[b2], 1);
            atomicAdd(&s_h[b3], 1);
        } else {
            for (int k = 0; k < 4; ++k) {
                int i = p0 + k;
                if (i < N) {
                    int b = compute_bid(xyz[3 * i], xyz[3 * i + 1], xyz[3 * i + 2],
                                        a0x, a0y, a0z, vx, vy, vz);
                    atomicAdd(&s_h[b], 1);
                }
            }
        }
    }
    __syncthreads();
    if (tid < NBUCK) hist[tid * G + g] = s_h[tid];
}

// Pass 2a: per-bucket row scan. Block b exclusive-scans hist[b*G .. b*G+G),
// in place, and writes the row total to tot[b].
__global__ void scan_rows_kernel(int* __restrict__ hist, int* __restrict__ tot, int G) {
    __shared__ int sh[BLK];
    const int b = blockIdx.x, t = threadIdx.x;
    const int L = (G + BLK - 1) / BLK;
    const int lo = t * L;
    const int n = min(L, max(0, G - lo));
    const int base = b * G + lo;
    int s = 0;
    for (int k = 0; k < n; ++k) s += hist[base + k];
    sh[t] = s;
    __syncthreads();
    for (int off = 1; off < BLK; off <<= 1) {
        int v = (t >= off) ? sh[t - off] : 0;
        __syncthreads();
        sh[t] += v;
        __syncthreads();
    }
    int excl = (t == 0) ? 0 : sh[t - 1];
    for (int k = 0; k < n; ++k) {
        int v = hist[base + k];
        hist[base + k] = excl;
        excl += v;
    }
    if (t == BLK - 1) tot[b] = sh[BLK - 1];
}

// Pass 2b: exclusive scan of the 64 bucket totals -> global bucket offsets.
__global__ void scan_buckets_kernel(const int* __restrict__ tot, int* __restrict__ off) {
    __shared__ int sh[NBUCK];
    const int t = threadIdx.x;
    sh[t] = tot[t];
    __syncthreads();
    for (int o = 1; o < NBUCK; o <<= 1) {
        int v = (t >= o) ? sh[t - o] : 0;
        __syncthreads();
        sh[t] += v;
        __syncthreads();
    }
    off[t] = (t == 0) ? 0 : sh[t - 1];
}

// Pass 3: stable in-tile scatter of the sample PAYLOAD:
// payload[pos] = (fx, fy, fz, bits(b)). Reads xyz coalesced, writes scattered
// 16B (same-bucket wave groups land contiguous; a tile fully covers its
// per-bucket output run, so L2 write-combines whole lines).
__global__ void scatter_payload_kernel(const float* __restrict__ xyz,
                                       const float* __restrict__ aabb,
                                       const float* __restrict__ dmin,
                                       const float* __restrict__ dmax,
                                       const int* __restrict__ hist,
                                       const int* __restrict__ off,
                                       float4* __restrict__ payload, int N, int G) {
    __shared__ int   s_cnt[NBUCK];      // running output offset per bucket
    __shared__ int   s_whist[4][NBUCK]; // per-wave per-bucket chunk counts
    __shared__ float s_dmin[192], s_dmax[192];
    const int tid = threadIdx.x, g = blockIdx.x;
    if (tid < NBUCK) s_cnt[tid] = hist[tid * G + g] + off[tid];
    for (int i = tid; i < 192; i += BLK) {
        s_dmin[i] = dmin[i];
        s_dmax[i] = dmax[i];
    }
    const float a0x = aabb[0], a0y = aabb[1], a0z = aabb[2];
    const float vx = (aabb[3] - a0x) * 0.25f;
    const float vy = (aabb[4] - a0y) * 0.25f;
    const float vz = (aabb[5] - a0z) * 0.25f;
    __syncthreads();

    const int lane = tid & 63;
    const int wv = tid >> 6;
    const unsigned long long lt = (1ull << lane) - 1ull;

    for (int c = 0; c < TILE / BLK; ++c) {
        int i = g * TILE + c * BLK + tid;
        bool valid = (i < N);
        int b = 0;
        float fx = 0.0f, fy = 0.0f, fz = 0.0f;
        if (valid) {
            float px = xyz[3 * i], py = xyz[3 * i + 1], pz = xyz[3 * i + 2];
            b = compute_bid(px, py, pz, a0x, a0y, a0z, vx, vy, vz);
            float dn0 = s_dmin[3 * b], dn1 = s_dmin[3 * b + 1], dn2 = s_dmin[3 * b + 2];
            float dM0 = s_dmax[3 * b], dM1 = s_dmax[3 * b + 1], dM2 = s_dmax[3 * b + 2];
            float lx = 2.0f * (px - dn0) / (dM0 - dn0) - 1.0f;
            float ly = 2.0f * (py - dn1) / (dM1 - dn1) - 1.0f;
            float lz = 2.0f * (pz - dn2) / (dM2 - dn2) - 1.0f;
            fx = (lx + 1.0f) * 0.5f * 63.0f;
            fy = (ly + 1.0f) * 0.5f * 63.0f;
            fz = (lz + 1.0f) * 0.5f * 63.0f;
        }
        ((int*)s_whist)[tid] = 0;
        __syncthreads();
        // match-any over the 6-bit bucket id within the wave
        unsigned long long m = __ballot(valid);
        #pragma unroll
        for (int k = 0; k < 6; ++k) {
            unsigned long long bal = __ballot((b >> k) & 1);
            m &= ((b >> k) & 1) ? bal : ~bal;
        }
        int rank = __popcll(m & lt);
        if (valid && rank == 0) s_whist[wv][b] = __popcll(m);
        __syncthreads();
        if (valid) {
            int pos = s_cnt[b] + rank;
            for (int w2 = 0; w2 < wv; ++w2) pos += s_whist[w2][b];
            payload[pos] = make_float4(fx, fy, fz, __int_as_float(b));
        }
        __syncthreads();
        if (tid < NBUCK)
            s_cnt[tid] += s_whist[0][tid] + s_whist[1][tid] +
                          s_whist[2][tid] + s_whist[3][tid];
        __syncthreads();
    }
}

// Pass 4: walk output in sorted order; coalesced payload read, bucket-local
// volume gathers, coalesced out write.
__global__ void gather_out_kernel(const float* __restrict__ vol,
                                  const float4* __restrict__ payload,
                                  float* __restrict__ out, int N) {
    // XCD swizzle: each XCD gets a contiguous range of sorted output so its
    // volume gathers stay within ~its own buckets' sub-volumes (L2-resident).
    int nb = gridDim.x;
    int d = blockIdx.x;
    int lb = (nb % 8 == 0) ? (d % 8) * (nb / 8) + (d / 8) : d;
    int j = lb * BLK + threadIdx.x;
    if (j >= N) return;
    float4 p = payload[j];
    float fx = p.x, fy = p.y, fz = p.z;
    int b = __float_as_int(p.w);
    float x0f = floorf(fx), y0f = floorf(fy), z0f = floorf(fz);
    float wx = fx - x0f, wy = fy - y0f, wz = fz - z0f;
    int x0 = (int)x0f, y0 = (int)y0f, z0 = (int)z0f;
    const float* vb = vol + ((size_t)b << 18);
    auto F = [&](int zi, int yi, int xi) -> float {
        if ((unsigned)zi >= 64u || (unsigned)yi >= 64u || (unsigned)xi >= 64u)
            return 0.0f;
        return vb[(zi << 12) + (yi << 6) + xi];
    };
    float s = 0.0f;
    s += (1.0f - wz) * (1.0f - wy) * (1.0f - wx) * F(z0,     y0,     x0);
    s += (1.0f - wz) * (1.0f - wy) * wx          * F(z0,     y0,     x0 + 1);
    s += (1.0f - wz) * wy          * (1.0f - wx) * F(z0,     y0 + 1, x0);
    s += (1.0f - wz) * wy          * wx          * F(z0,     y0 + 1, x0 + 1);
    s += wz          * (1.0f - wy) * (1.0f - wx) * F(z0 + 1, y0,     x0);
    s += wz          * (1.0f - wy) * wx          * F(z0 + 1, y0,     x0 + 1);
    s += wz          * wy          * (1.0f - wx) * F(z0 + 1, y0 + 1, x0);
    s += wz          * wy          * wx          * F(z0 + 1, y0 + 1, x0 + 1);
    out[j] = s;
}

extern "C" void kernel_launch(void* const* d_in, const int* in_sizes, int n_in,
                              void* d_out, int out_size, void* d_ws, size_t ws_size,
                              hipStream_t stream) {
    const float* xyz  = (const float*)d_in[0];
    const float* aabb = (const float*)d_in[1];
    const float* vol  = (const float*)d_in[2];
    const float* dmin = (const float*)d_in[3];
    const float* dmax = (const float*)d_in[4];
    float* out = (float*)d_out;
    const int N = in_sizes[0] / 3;
    const int G = (N + TILE - 1) / TILE;

    // ws layout: payload[N] float4 (16B-aligned at base) | hist[64*G] | tot[64] | off[64]
    char* ws = (char*)d_ws;
    float4* payload = (float4*)ws;
    int* hist = (int*)(ws + (size_t)N * 16);
    int* tot  = (int*)(ws + (size_t)N * 16 + (size_t)NBUCK * G * 4);
    int* off  = (int*)(ws + (size_t)N * 16 + (size_t)NBUCK * G * 4 + 256);

    hist_kernel<<<G, BLK, 0, stream>>>(xyz, aabb, hist, N, G);
    scan_rows_kernel<<<NBUCK, BLK, 0, stream>>>(hist, tot, G);
    scan_buckets_kernel<<<1, NBUCK, 0, stream>>>(tot, off);
    scatter_payload_kernel<<<G, BLK, 0, stream>>>(xyz, aabb, dmin, dmax, hist, off,
                                                  payload, N, G);
    gather_out_kernel<<<(N + BLK - 1) / BLK, BLK, 0, stream>>>(vol, payload, out, N);
}